// Round 1
// 169.016 us; speedup vs baseline: 1.1081x; 1.1081x over previous
//
#include <hip/hip_runtime.h>

#define NB    128
#define NT    8192
#define TPB   256
#define CHUNK 32

// XOR swizzle: flips bits [2:4] of the element index with the low 3 bits of
// the 32-element-row index. Keeps float4 groups contiguous & 16B aligned,
// makes both access patterns (coalesced k*1024+tid*4 and per-thread
// contiguous chunk tid*32+4j) <=2-way bank conflicts (free on wave64).
__device__ __forceinline__ int swz(int n) { return n ^ (((n >> 5) & 7) << 2); }

// One block per (b, f, t) plane: 8 * 128 * 4 = 4096 blocks.
// Single-rate per block -> 3 barriers total (vs 24 in the 4-rate version),
// shuffle-based scan, 4 residency waves of blocks for inter-block overlap.
__global__ __launch_bounds__(TPB, 4) void mrpcen_kernel(
    const float* __restrict__ x,
    const float* __restrict__ log_alpha,
    const float* __restrict__ log_delta,
    const float* __restrict__ log_r,
    float* __restrict__ out)
{
    __shared__ __align__(16) float sh[NT];  // 32 KiB: x staging, then out staging
    __shared__ float sWagg[4];              // cross-wave scan aggregates

    const int tid  = threadIdx.x;
    const int lane = tid & 63;
    const int wid  = tid >> 6;

    const int bft = blockIdx.x;            // 0..4095
    const int t   = bft & 3;
    const int f   = (bft >> 2) & (NB - 1);
    const int b   = bft >> 9;

    const float* xrow = x + (size_t)(b * NB + f) * NT;

    // per-band params (stored in log space)
    const float alpha  = __expf(log_alpha[f]);
    const float r      = __expf(log_r[f]);
    const float delta  = __expf(log_delta[f]);
    const float deltar = __expf(r * log_delta[f]);   // delta^r, exact from log param

    // this block's rate: t_vals = {2,8,32,128} = 2 << 2t
    const float tt = (float)(2 << (2 * t));
    const float t2 = tt * tt;
    const float s  = (sqrtf(1.f + 4.f * t2) - 1.f) / (2.f * t2);
    const float a1 = 1.f - s;
    float A = a1;                                    // (1-s)^32 via 5 squarings
    A = A * A; A = A * A; A = A * A; A = A * A; A = A * A;

    // ---- 1. coalesced global -> LDS (swizzled) ----
#pragma unroll
    for (int k = 0; k < 8; k++) {
        int n = k * 1024 + tid * 4;
        float4 v = *reinterpret_cast<const float4*>(xrow + n);
        *reinterpret_cast<float4*>(&sh[swz(n)]) = v;
    }
    __syncthreads();   // barrier 1

    const float x0 = sh[0];   // swz(0)==0; scan carry init m[-1] = x[0]

    // ---- 2. own contiguous chunk into registers ----
    float xc[CHUNK];
#pragma unroll
    for (int j = 0; j < 8; j++) {
        int n = tid * CHUNK + 4 * j;
        float4 v = *reinterpret_cast<const float4*>(&sh[swz(n)]);
        xc[4 * j + 0] = v.x; xc[4 * j + 1] = v.y;
        xc[4 * j + 2] = v.z; xc[4 * j + 3] = v.w;
    }

    // ---- 3. local affine compose (B with m_in = 0) ----
    float Bl = 0.f;
#pragma unroll
    for (int i = 0; i < CHUNK; i++)
        Bl = s * xc[i] + a1 * Bl;

    // ---- 4. block scan S[i] = B[i] + A*S[i-1] ----
    // in-wave Kogge-Stone via shuffles (no barriers), cross-wave via LDS.
    float v = Bl;
    float ap = A;
#pragma unroll
    for (int d = 1; d < 64; d <<= 1) {
        float up = __shfl_up(v, d);
        if (lane >= d) v += ap * up;
        ap *= ap;
    }
    const float a64 = ap;                 // A^64 falls out of the 6 squarings
    if (lane == 63) sWagg[wid] = v;
    __syncthreads();   // barrier 2 (also separates all sh x-reads from stage-out)

    const float W0 = sWagg[0], W1 = sWagg[1], W2 = sWagg[2];
    float pre = 0.f;                      // affine-composed prefix of earlier waves
    if (wid >= 1) pre = W0;
    if (wid >= 2) pre = a64 * pre + W1;
    if (wid >= 3) pre = a64 * pre + W2;

    // A^lane by binary powering (6 bits)
    float pl = 1.f, base = A;
    int e = lane;
#pragma unroll
    for (int bit = 0; bit < 6; bit++) {
        if (e & 1) pl *= base;
        base *= base;
        e >>= 1;
    }
    // A^(64*wid), wid in 0..3
    float aw = 1.f;
    const float a128 = a64 * a64;
    if (wid & 1) aw *= a64;
    if (wid & 2) aw *= a128;

    // m_in = A^tid * x0 + S[tid-1]
    //      = pl*(aw*x0 + pre) + (in-wave exclusive term)
    const float vprev = __shfl_up(v, 1);
    float m = pl * (aw * x0 + pre) + ((lane > 0) ? vprev : 0.f);

    // ---- 5. recurrence + epilogue in regs, stage in sh, coalesced store ----
#pragma unroll
    for (int j = 0; j < 8; j++) {
        float ov[4];
#pragma unroll
        for (int q = 0; q < 4; q++) {
            float xi = xc[4 * j + q];
            m = s * xi + a1 * m;
            // smooth = (eps + m)^(-alpha)
            float smooth = __expf(-alpha * __logf(1e-5f + m));
            // pcen = (x*smooth + delta)^r - delta^r   (arg >= delta = 10 > 0)
            ov[q] = __expf(r * __logf(xi * smooth + delta)) - deltar;
        }
        // own region of sh only -> no barrier needed before these writes
        *reinterpret_cast<float4*>(&sh[swz(tid * CHUNK + 4 * j)]) =
            make_float4(ov[0], ov[1], ov[2], ov[3]);
    }
    __syncthreads();   // barrier 3

    float* oplane = out + (((size_t)b * 4 + t) * NB + f) * (size_t)NT;
#pragma unroll
    for (int k = 0; k < 8; k++) {
        int n = k * 1024 + tid * 4;
        float4 o = *reinterpret_cast<const float4*>(&sh[swz(n)]);
        *reinterpret_cast<float4*>(oplane + n) = o;
    }
}

extern "C" void kernel_launch(void* const* d_in, const int* in_sizes, int n_in,
                              void* d_out, int out_size, void* d_ws, size_t ws_size,
                              hipStream_t stream) {
    const float* x         = (const float*)d_in[0];
    const float* log_alpha = (const float*)d_in[1];
    const float* log_delta = (const float*)d_in[2];
    const float* log_r     = (const float*)d_in[3];
    float* out = (float*)d_out;

    // one block per (b, f, t) plane: 8 * 128 * 4 = 4096 blocks
    mrpcen_kernel<<<dim3(8 * NB * 4), dim3(TPB), 0, stream>>>(
        x, log_alpha, log_delta, log_r, out);
}

// Round 3
// 163.812 us; speedup vs baseline: 1.1433x; 1.0318x over previous
//
#include <hip/hip_runtime.h>

#define NB    128
#define NT    8192
#define TPB   512
#define CHUNK 16

// Raw gfx950 transcendentals: v_exp_f32 computes 2^x, v_log_f32 computes log2(x).
// (HIP has no __exp2f intrinsic -- that name collides with glibc's math.h.)
__device__ __forceinline__ float fexp2(float x) { return __builtin_amdgcn_exp2f(x); }
__device__ __forceinline__ float flog2(float x) { return __builtin_amdgcn_logf(x); }

// XOR swizzle on float index: flips bits [4:2] with bits [7:5]. Spreads both
// staging patterns (write lane*16+4j, read k*256+lane*4) evenly across the
// 8 16B-bank-groups -> no serializing LDS conflicts. Keeps float4 groups
// contiguous & 16B aligned. Operates within 256-float tiles, so per-wave
// 1024-float regions stay self-contained.
__device__ __forceinline__ int swz(int n) { return n ^ (((n >> 5) & 7) << 2); }

// One block per (b, f, t) plane: 8 * 128 * 4 = 4096 blocks of 512 threads.
// CHUNK=16 keeps VGPRs under the 64-reg cliff -> 8 waves/SIMD -> 4 blocks/CU
// = 32 waves/CU (100% occupancy). Input: direct strided loads (no staging).
// Output: per-wave LDS staging (intra-wave exchange only -> no barrier).
// Exactly ONE __syncthreads (cross-wave scan handoff).
__global__ __launch_bounds__(TPB, 8) void mrpcen_kernel(
    const float* __restrict__ x,
    const float* __restrict__ log_alpha,
    const float* __restrict__ log_delta,
    const float* __restrict__ log_r,
    float* __restrict__ out)
{
    __shared__ __align__(16) float sh[NT];  // 32 KiB out staging, per-wave 4KB slices
    __shared__ float sWagg[8];              // cross-wave scan aggregates

    const int tid  = threadIdx.x;
    const int lane = tid & 63;
    const int wid  = tid >> 6;

    const int bft = blockIdx.x;             // 0..4095
    const int t   = bft & 3;
    const int f   = (bft >> 2) & (NB - 1);
    const int b   = bft >> 9;

    const float* xrow = x + (size_t)(b * NB + f) * NT;

    // per-band params (stored in log space)
    const float alpha  = __expf(log_alpha[f]);
    const float r      = __expf(log_r[f]);
    const float delta  = __expf(log_delta[f]);
    const float deltar = __expf(r * log_delta[f]);   // delta^r, exact from log param
    const float nalpha = -alpha;

    // this block's rate: t_vals = {2,8,32,128} = 2 << 2t
    const float tt = (float)(2 << (2 * t));
    const float t2 = tt * tt;
    const float s  = (sqrtf(1.f + 4.f * t2) - 1.f) / (2.f * t2);
    const float a1 = 1.f - s;
    float A = a1;                                    // (1-s)^16 via 4 squarings
    A = A * A; A = A * A; A = A * A; A = A * A;

    // ---- 1. direct strided global loads: lane's own 16 contiguous floats ----
    // lane-stride 64B; each 64B line fully consumed by one lane across j=0..3.
    float xc[CHUNK];
#pragma unroll
    for (int j = 0; j < 4; j++) {
        float4 v = *reinterpret_cast<const float4*>(xrow + tid * CHUNK + 4 * j);
        xc[4 * j + 0] = v.x; xc[4 * j + 1] = v.y;
        xc[4 * j + 2] = v.z; xc[4 * j + 3] = v.w;
    }
    const float x0 = xrow[0];   // uniform address -> scalar load; m[-1] = x[0]

    // ---- 2. local affine compose (B with m_in = 0) ----
    float Bl = 0.f;
#pragma unroll
    for (int i = 0; i < CHUNK; i++)
        Bl = s * xc[i] + a1 * Bl;

    // ---- 3. in-wave Kogge-Stone scan via shuffles (no barriers) ----
    float v = Bl;
    float ap = A;
#pragma unroll
    for (int d = 1; d < 64; d <<= 1) {
        float up = __shfl_up(v, d);
        if (lane >= d) v += ap * up;
        ap *= ap;
    }
    const float a64 = ap;                 // A^64 falls out of the 6 squarings
    if (lane == 63) sWagg[wid] = v;
    __syncthreads();                      // the ONLY block barrier

    // cross-wave exclusive prefix: fold waves 0..wid-1 (wave-uniform branches)
    float pre = 0.f;
#pragma unroll
    for (int k = 0; k < 7; k++)
        if (wid > k) pre = a64 * pre + sWagg[k];

    // A^lane by binary powering (6 bits)
    float pl = 1.f, base = A;
    int e = lane;
#pragma unroll
    for (int bit = 0; bit < 6; bit++) {
        if (e & 1) pl *= base;
        base *= base;
        e >>= 1;
    }
    // a64^wid (3 bits)
    float aw = 1.f, wb = a64;
    e = wid;
#pragma unroll
    for (int bit = 0; bit < 3; bit++) {
        if (e & 1) aw *= wb;
        wb *= wb;
        e >>= 1;
    }

    // m_in = A^lane * (a64^wid * x0 + pre) + in-wave exclusive term
    const float vprev = __shfl_up(v, 1);
    float m = pl * (aw * x0 + pre) + ((lane > 0) ? vprev : 0.f);

    // ---- 4. recurrence + epilogue, stage into own wave slice of sh ----
    // exp(-a*ln z) = exp2(-a*log2 z): native v_log_f32/v_exp_f32, no 0.693 muls
#pragma unroll
    for (int j = 0; j < 4; j++) {
        float ov[4];
#pragma unroll
        for (int q = 0; q < 4; q++) {
            float xi = xc[4 * j + q];
            m = s * xi + a1 * m;
            float smooth = fexp2(nalpha * flog2(1e-5f + m));
            // pcen = (x*smooth + delta)^r - delta^r   (arg >= delta > 0)
            ov[q] = fexp2(r * flog2(xi * smooth + delta)) - deltar;
        }
        *reinterpret_cast<float4*>(&sh[swz(tid * CHUNK + 4 * j)]) =
            make_float4(ov[0], ov[1], ov[2], ov[3]);
    }

    // ---- 5. coalesced store from own wave's slice ----
    // Intra-wave exchange only: this wave's ds_writes are drained by the
    // compiler's lgkmcnt before the ds_reads below; no __syncthreads needed.
    float* oplane = out + (((size_t)b * 4 + t) * NB + f) * (size_t)NT;
    const int wbase = wid << 10;          // wave's 1024-float region
#pragma unroll
    for (int k = 0; k < 4; k++) {
        int n = wbase + k * 256 + lane * 4;
        float4 o = *reinterpret_cast<const float4*>(&sh[swz(n)]);
        *reinterpret_cast<float4*>(oplane + n) = o;
    }
}

extern "C" void kernel_launch(void* const* d_in, const int* in_sizes, int n_in,
                              void* d_out, int out_size, void* d_ws, size_t ws_size,
                              hipStream_t stream) {
    const float* x         = (const float*)d_in[0];
    const float* log_alpha = (const float*)d_in[1];
    const float* log_delta = (const float*)d_in[2];
    const float* log_r     = (const float*)d_in[3];
    float* out = (float*)d_out;

    // one block per (b, f, t) plane: 8 * 128 * 4 = 4096 blocks
    mrpcen_kernel<<<dim3(8 * NB * 4), dim3(TPB), 0, stream>>>(
        x, log_alpha, log_delta, log_r, out);
}